// Round 1
// baseline (2722.156 us; speedup 1.0000x reference)
//
#include <hip/hip_runtime.h>
#include <hip/hip_bf16.h>

#define LSEQ 318
#define NBATCH 128
#define NE (NBATCH * LSEQ) // 40704 elements per channel for BN stats

// ---------------------------------------------------------------------------
// Stem: conv1d(x[128,1,5087], w[16,1,1700], pad=850) + maxpool16 (+b0)
// Writes pre[128][16][318] (pre-BN). Each block: one n, 16 pooled outputs
// (256 conv positions). Thread: co = t&15, 16 consecutive conv positions
// (= exactly one pool window). Rolling float4 window over LDS-staged x.
// ---------------------------------------------------------------------------
__global__ __launch_bounds__(256) void stem_kernel(
    const float* __restrict__ x, const float* __restrict__ w,
    const float* __restrict__ b0, float* __restrict__ pre)
{
  const int KC = 160, KCP = 164; // k-chunk and padded LDS stride (bank spread)
  __shared__ __align__(16) float ws[16 * 164];
  __shared__ __align__(16) float xs[448];
  int t = threadIdx.x;
  int n = blockIdx.y;
  int q0 = blockIdx.x * 16;      // pooled output base
  int p0 = q0 * 16;              // conv position base (256 positions/block)
  int co = t & 15;
  int pb = (t >> 4) * 16;        // local conv-position base (= pool window)
  float acc[16];
#pragma unroll
  for (int i = 0; i < 16; ++i) acc[i] = 0.f;
  const float* xn = x + (size_t)n * 5087;

  for (int k0 = 0; k0 < 1760; k0 += KC) { // 11 chunks, tail zero-padded
    __syncthreads();
    for (int e = t; e < 16 * KCP; e += 256) {
      int cco = e / KCP;
      int k = e - cco * KCP;
      int kg = k0 + k;
      float v = 0.f;
      if (k < KC && kg < 1700) v = w[cco * 1700 + kg];
      ws[e] = v;
    }
    for (int i = t; i < 448; i += 256) {
      int gx = p0 + k0 - 850 + i;   // zero padding of 850 on both sides
      xs[i] = (gx >= 0 && gx < 5087) ? xn[gx] : 0.f;
    }
    __syncthreads();

    float4 xv[5];
#pragma unroll
    for (int j = 0; j < 5; ++j) xv[j] = *(const float4*)&xs[pb + 4 * j];
    const float* wr = &ws[co * KCP];
#pragma unroll 5
    for (int g = 0; g < 40; ++g) {
      float4 wv = *(const float4*)&wr[g * 4];
#pragma unroll
      for (int dk = 0; dk < 4; ++dk) {
        float wk = (dk == 0) ? wv.x : (dk == 1) ? wv.y : (dk == 2) ? wv.z : wv.w;
#pragma unroll
        for (int j = 0; j < 16; ++j) {
          int o = dk + j;
          float4 xq = xv[o >> 2];
          int om = o & 3;
          float xe = (om == 0) ? xq.x : (om == 1) ? xq.y : (om == 2) ? xq.z : xq.w;
          acc[j] = fmaf(xe, wk, acc[j]);
        }
      }
      xv[0] = xv[1]; xv[1] = xv[2]; xv[2] = xv[3]; xv[3] = xv[4];
      xv[4] = *(const float4*)&xs[pb + 4 * g + 20];
    }
  }
  // maxpool over the thread's 16 conv positions (one pool window), + b0
  float m = acc[0];
#pragma unroll
  for (int i = 1; i < 16; ++i) m = fmaxf(m, acc[i]);
  int q = q0 + (t >> 4);
  if (q < LSEQ) pre[((size_t)n * 16 + co) * LSEQ + q] = m + b0[co];
}

// ---------------------------------------------------------------------------
// k=3 conv, pad=1 (cross-correlation): dst[n][co][l] = sum_{ci,t} src[n][ci][l+t-1]*w[co][ci][t]
// src [B][Cin][318], w [32][Cin][3], dst [B][32][318].
// One wave/block; lane = l; 16 co accumulators; w indices are thread-uniform -> s_load.
// grid: (5 l-tiles, 2 co-halves, 128 n), block 64.
// ---------------------------------------------------------------------------
__global__ __launch_bounds__(64) void conv_k3(
    const float* __restrict__ src, int Cin,
    const float* __restrict__ w, float* __restrict__ dst)
{
  int lane = threadIdx.x;
  int l = blockIdx.x * 64 + lane;
  int co0 = blockIdx.y * 16;
  int n = blockIdx.z;
  const float* xb = src + (size_t)n * Cin * LSEQ;
  bool lv = (l < LSEQ);
  float acc[16];
#pragma unroll
  for (int i = 0; i < 16; ++i) acc[i] = 0.f;
  for (int ci = 0; ci < Cin; ++ci) {
    const float* xr = xb + (size_t)ci * LSEQ;
    float xm = (lv && l >= 1) ? xr[l - 1] : 0.f;
    float x0 = lv ? xr[l] : 0.f;
    float xp = (lv && l < LSEQ - 1) ? xr[l + 1] : 0.f;
    const float* wr = w + ((size_t)co0 * Cin + ci) * 3;
#pragma unroll
    for (int cc = 0; cc < 16; ++cc) {
      float w0 = wr[(size_t)cc * Cin * 3 + 0]; // uniform -> scalar load
      float w1 = wr[(size_t)cc * Cin * 3 + 1];
      float w2 = wr[(size_t)cc * Cin * 3 + 2];
      acc[cc] = fmaf(xm, w0, acc[cc]);
      acc[cc] = fmaf(x0, w1, acc[cc]);
      acc[cc] = fmaf(xp, w2, acc[cc]);
    }
  }
  if (lv) {
    float* d = dst + ((size_t)n * 32 + co0) * LSEQ + l;
#pragma unroll
    for (int cc = 0; cc < 16; ++cc) d[(size_t)cc * LSEQ] = acc[cc];
  }
}

// ---------------------------------------------------------------------------
// convT(k=3, stride1, pad1) of src tail-32 channels + head passthrough:
// dst[n][c][l] = src[n][c][l] + sum_{j,t} src[n][Cout+j][l+t-1] * F[j][c][2-t]
// F [32][Cout][3]. grid: (5 l-tiles, Cout/16, 128 n), block 64.
// ---------------------------------------------------------------------------
__global__ __launch_bounds__(64) void convT_add(
    const float* __restrict__ src, int Cout,
    const float* __restrict__ F, float* __restrict__ dst)
{
  int lane = threadIdx.x;
  int l = blockIdx.x * 64 + lane;
  int c0 = blockIdx.y * 16;
  int n = blockIdx.z;
  int Csrc = Cout + 32;
  const float* xb = src + (size_t)n * Csrc * LSEQ;
  bool lv = (l < LSEQ);
  float acc[16];
#pragma unroll
  for (int i = 0; i < 16; ++i) acc[i] = 0.f;
  for (int j = 0; j < 32; ++j) {
    const float* xr = xb + (size_t)(Cout + j) * LSEQ;
    float xm = (lv && l >= 1) ? xr[l - 1] : 0.f;
    float x0 = lv ? xr[l] : 0.f;
    float xp = (lv && l < LSEQ - 1) ? xr[l + 1] : 0.f;
    const float* Fr = F + ((size_t)j * Cout + c0) * 3;
#pragma unroll
    for (int cc = 0; cc < 16; ++cc) {
      float w0 = Fr[cc * 3 + 2]; // t=0 -> 2-t=2
      float w1 = Fr[cc * 3 + 1];
      float w2 = Fr[cc * 3 + 0];
      acc[cc] = fmaf(xm, w0, acc[cc]);
      acc[cc] = fmaf(x0, w1, acc[cc]);
      acc[cc] = fmaf(xp, w2, acc[cc]);
    }
  }
  if (lv) {
    float* d = dst + ((size_t)n * Cout + c0) * LSEQ + l;
    const float* h = xb + (size_t)c0 * LSEQ + l;
#pragma unroll
    for (int cc = 0; cc < 16; ++cc) d[(size_t)cc * LSEQ] = acc[cc] + h[(size_t)cc * LSEQ];
  }
}

// pre[n][ch][l] = c * (ch<Cin ? head : tail[ch-Cin]) + bv[ch]
__global__ void cat_scale(const float* __restrict__ head, int Cin,
                          const float* __restrict__ tail,
                          const float* __restrict__ cs, const float* __restrict__ bv,
                          float* __restrict__ pre, int Ct)
{
  size_t idx = (size_t)blockIdx.x * 256 + threadIdx.x;
  size_t tot = (size_t)NBATCH * Ct * LSEQ;
  if (idx >= tot) return;
  int l = (int)(idx % LSEQ);
  size_t r = idx / LSEQ;
  int ch = (int)(r % Ct);
  int n = (int)(r / Ct);
  float v = (ch < Cin) ? head[((size_t)n * Cin + ch) * LSEQ + l]
                       : tail[((size_t)n * 32 + (ch - Cin)) * LSEQ + l];
  pre[idx] = cs[0] * v + bv[ch];
}

// f7 = feats[i+1] - c*(f4 - f6) + bv, f4=[t2; t3], f6=[fi; t4]
__global__ void f7_kernel(const float* __restrict__ fi1, int Cin,
                          const float* __restrict__ t2, const float* __restrict__ t3,
                          const float* __restrict__ t4, const float* __restrict__ fi,
                          const float* __restrict__ cs, const float* __restrict__ bv,
                          float* __restrict__ pre)
{
  int Ct = Cin + 32;
  size_t idx = (size_t)blockIdx.x * 256 + threadIdx.x;
  size_t tot = (size_t)NBATCH * Ct * LSEQ;
  if (idx >= tot) return;
  int l = (int)(idx % LSEQ);
  size_t r = idx / LSEQ;
  int ch = (int)(r % Ct);
  int n = (int)(r / Ct);
  float base = fi1[((size_t)n * Ct + ch) * LSEQ + l];
  float d;
  if (ch < Cin)
    d = t2[((size_t)n * Cin + ch) * LSEQ + l] - fi[((size_t)n * Cin + ch) * LSEQ + l];
  else
    d = t3[((size_t)n * 32 + (ch - Cin)) * LSEQ + l] - t4[((size_t)n * 32 + (ch - Cin)) * LSEQ + l];
  pre[idx] = base - cs[0] * d + bv[ch];
}

// per-channel sum / sumsq over (N, L); one block per channel
__global__ __launch_bounds__(256) void bn_stats(const float* __restrict__ pre, int C,
                                                float* __restrict__ stats)
{
  int c = blockIdx.x;
  int t = threadIdx.x;
  float s = 0.f, q = 0.f;
  for (int i = t; i < NE; i += 256) {
    int n = i / LSEQ, l = i - (i / LSEQ) * LSEQ;
    float v = pre[((size_t)n * C + c) * LSEQ + l];
    s += v; q += v * v;
  }
  __shared__ float ls[256], lq[256];
  ls[t] = s; lq[t] = q;
  __syncthreads();
  for (int st = 128; st > 0; st >>= 1) {
    if (t < st) { ls[t] += ls[t + st]; lq[t] += lq[t + st]; }
    __syncthreads();
  }
  if (t == 0) { stats[c * 2] = ls[0]; stats[c * 2 + 1] = lq[0]; }
}

__global__ void bn_apply(const float* __restrict__ pre, const float* __restrict__ stats,
                         const float* __restrict__ g, const float* __restrict__ b,
                         float* __restrict__ out, int C, int relu)
{
  size_t idx = (size_t)blockIdx.x * 256 + threadIdx.x;
  size_t tot = (size_t)NBATCH * C * LSEQ;
  if (idx >= tot) return;
  size_t r = idx / LSEQ;
  int ch = (int)(r % C);
  float m = stats[ch * 2] * (1.f / NE);
  float var = stats[ch * 2 + 1] * (1.f / NE) - m * m;
  float rs = rsqrtf(var + 1e-5f);
  float v = (pre[idx] - m) * rs * g[ch] + b[ch];
  out[idx] = relu ? fmaxf(v, 0.f) : v;
}

// eSE mean over L: sm[n][c]
__global__ __launch_bounds__(64) void ese_mean(const float* __restrict__ z, float* __restrict__ sm)
{
  int c = blockIdx.x;   // 112
  int n = blockIdx.y;   // 128
  int lane = threadIdx.x;
  const float* r = z + ((size_t)n * 112 + c) * LSEQ;
  float s = 0.f;
  for (int l = lane; l < LSEQ; l += 64) s += r[l];
  for (int off = 32; off > 0; off >>= 1) s += __shfl_down(s, off);
  if (lane == 0) sm[n * 112 + c] = s * (1.f / LSEQ);
}

// a[n][c] = clip(sm@W.T + b + 3, 0, 6)/6
__global__ __launch_bounds__(128) void ese_act(const float* __restrict__ sm,
                                               const float* __restrict__ W,
                                               const float* __restrict__ b,
                                               float* __restrict__ am)
{
  int n = blockIdx.x;
  int c = threadIdx.x;
  if (c >= 112) return;
  const float* s = sm + n * 112;
  float a = b[c] + 3.0f;
  for (int cc = 0; cc < 112; ++cc) a = fmaf(s[cc], W[c * 112 + cc], a);
  a = fminf(fmaxf(a, 0.f), 6.f) * (1.f / 6.f);
  am[n * 112 + c] = a;
}

// fc1 GEMM: y1[n][j] += sum_k zflat[n][k]*w1[j][k], zflat = z * eSE scale (fused).
// split-K over 128 blocks, 32x(128x128) tile staged in LDS, 8x8 per-thread.
__global__ __launch_bounds__(256) void fc1_gemm(const float* __restrict__ z,
                                                const float* __restrict__ am,
                                                const float* __restrict__ w1,
                                                float* __restrict__ y1)
{
  __shared__ __align__(16) float zs[32 * 132];
  __shared__ __align__(16) float wsh[32 * 132];
  int t = threadIdx.x;
  int blk = blockIdx.x;
  int k0 = blk * 279;
  int kend = k0 + 279; if (kend > 35616) kend = 35616;
  int ng = t & 15, jg = t >> 4;
  float acc[8][8];
#pragma unroll
  for (int i = 0; i < 8; ++i)
#pragma unroll
    for (int j = 0; j < 8; ++j) acc[i][j] = 0.f;

  for (int ks = k0; ks < kend; ks += 32) {
    __syncthreads();
    for (int e = t; e < 4096; e += 256) {
      int row = e >> 5, kk = e & 31;
      int k = ks + kk;
      float zv = 0.f, wv = 0.f;
      if (k < kend) {
        int c = k / LSEQ, l = k - c * LSEQ;
        zv = z[((size_t)row * 112 + c) * LSEQ + l] * am[row * 112 + c];
        wv = w1[(size_t)row * 35616 + k];
      }
      zs[kk * 132 + row] = zv;
      wsh[kk * 132 + row] = wv;
    }
    __syncthreads();
    for (int kk = 0; kk < 32; ++kk) {
      float4 za = *(const float4*)&zs[kk * 132 + ng * 8];
      float4 zb = *(const float4*)&zs[kk * 132 + ng * 8 + 4];
      float4 wa = *(const float4*)&wsh[kk * 132 + jg * 8];
      float4 wb = *(const float4*)&wsh[kk * 132 + jg * 8 + 4];
      float zr[8] = {za.x, za.y, za.z, za.w, zb.x, zb.y, zb.z, zb.w};
      float wr[8] = {wa.x, wa.y, wa.z, wa.w, wb.x, wb.y, wb.z, wb.w};
#pragma unroll
      for (int i = 0; i < 8; ++i)
#pragma unroll
        for (int j = 0; j < 8; ++j) acc[i][j] = fmaf(zr[i], wr[j], acc[i][j]);
    }
  }
#pragma unroll
  for (int i = 0; i < 8; ++i)
#pragma unroll
    for (int j = 0; j < 8; ++j)
      atomicAdd(&y1[(ng * 8 + i) * 128 + jg * 8 + j], acc[i][j]);
}

// fc2 + log_softmax; writes both outputs (lsm then logits)
__global__ __launch_bounds__(128) void fc2_lsm(const float* __restrict__ y1,
                                               const float* __restrict__ b1,
                                               const float* __restrict__ w2,
                                               const float* __restrict__ b2,
                                               float* __restrict__ out)
{
  int n = blockIdx.x;
  int t = threadIdx.x; // 128
  __shared__ float part[10][128];
  float v = fmaxf(y1[n * 128 + t] + b1[t], 0.f);
#pragma unroll
  for (int k = 0; k < 10; ++k) part[k][t] = v * w2[k * 128 + t];
  __syncthreads();
  for (int st = 64; st > 0; st >>= 1) {
    if (t < st) {
#pragma unroll
      for (int k = 0; k < 10; ++k) part[k][t] += part[k][t + st];
    }
    __syncthreads();
  }
  if (t == 0) {
    float lg[10];
    float mx = -1e30f;
#pragma unroll
    for (int k = 0; k < 10; ++k) { lg[k] = part[k][0] + b2[k]; mx = fmaxf(mx, lg[k]); }
    float s = 0.f;
#pragma unroll
    for (int k = 0; k < 10; ++k) s += expf(lg[k] - mx);
    float ls = logf(s) + mx;
#pragma unroll
    for (int k = 0; k < 10; ++k) {
      out[n * 10 + k] = lg[k] - ls;
      out[1280 + n * 10 + k] = lg[k];
    }
  }
}

extern "C" void kernel_launch(void* const* d_in, const int* in_sizes, int n_in,
                              void* d_out, int out_size, void* d_ws, size_t ws_size,
                              hipStream_t stream)
{
  (void)in_sizes; (void)n_in; (void)out_size; (void)ws_size;
  const float* x       = (const float*)d_in[0];
  const float* filter0 = (const float*)d_in[1];
  const float* b0      = (const float*)d_in[2];
  const float* bn0_g   = (const float*)d_in[3];
  const float* bn0_b   = (const float*)d_in[4];
  const float* ese_w   = (const float*)d_in[5];
  const float* ese_b   = (const float*)d_in[6];
  const float* fc1_w   = (const float*)d_in[7];
  const float* fc1_b   = (const float*)d_in[8];
  const float* fc2_w   = (const float*)d_in[9];
  const float* fc2_b   = (const float*)d_in[10];
  const float* F[3]    = {(const float*)d_in[11], (const float*)d_in[16], (const float*)d_in[21]};
  const float* bv[3]   = {(const float*)d_in[12], (const float*)d_in[17], (const float*)d_in[22]};
  const float* g1[3]   = {(const float*)d_in[13], (const float*)d_in[18], (const float*)d_in[23]};
  const float* be1[3]  = {(const float*)d_in[14], (const float*)d_in[19], (const float*)d_in[24]};
  const float* cs[3]   = {(const float*)d_in[15], (const float*)d_in[20], (const float*)d_in[25]};

  float* wsf = (float*)d_ws;
  size_t o = 0;
  float* f0 = wsf + o;   o += (size_t)128 * 16 * LSEQ;
  float* f1 = wsf + o;   o += (size_t)128 * 48 * LSEQ;
  float* f2 = wsf + o;   o += (size_t)128 * 80 * LSEQ;
  float* f3 = wsf + o;   o += (size_t)128 * 112 * LSEQ;
  float* t2 = wsf + o;   o += (size_t)128 * 80 * LSEQ;
  float* t3 = wsf + o;   o += (size_t)128 * 32 * LSEQ;
  float* t4 = wsf + o;   o += (size_t)128 * 32 * LSEQ;
  float* pre = wsf + o;  o += (size_t)128 * 112 * LSEQ;
  float* stats = wsf + o; o += 256;
  float* sm = wsf + o;   o += 128 * 112;
  float* am = wsf + o;   o += 128 * 112;
  float* y1 = wsf + o;   o += 128 * 128;

  float* feats[4] = {f0, f1, f2, f3};
  const int C[4] = {16, 48, 80, 112};

  // ---- stem: conv + maxpool + BN (no relu) ----
  stem_kernel<<<dim3(20, 128), 256, 0, stream>>>(x, filter0, b0, pre);
  bn_stats<<<16, 256, 0, stream>>>(pre, 16, stats);
  {
    size_t tot = (size_t)128 * 16 * LSEQ;
    bn_apply<<<(int)((tot + 255) / 256), 256, 0, stream>>>(pre, stats, bn0_g, bn0_b, f0, 16, 0);
  }

  // ---- initial ISTA stages ----
  for (int i = 0; i < 3; ++i) {
    conv_k3<<<dim3(5, 2, 128), 64, 0, stream>>>(feats[i], C[i], F[i], t3);
    int Ct = C[i + 1];
    size_t tot = (size_t)128 * Ct * LSEQ;
    cat_scale<<<(int)((tot + 255) / 256), 256, 0, stream>>>(feats[i], C[i], t3, cs[i], bv[i], pre, Ct);
    bn_stats<<<Ct, 256, 0, stream>>>(pre, Ct, stats);
    bn_apply<<<(int)((tot + 255) / 256), 256, 0, stream>>>(pre, stats, g1[i], be1[i], feats[i + 1], Ct, 1);
  }

  // ---- unfolding iterations ----
  for (int u = 0; u < 3; ++u) {
    // backward reconstruction
    convT_add<<<dim3(5, 80 / 16, 128), 64, 0, stream>>>(f3, 80, F[2], f2);
    convT_add<<<dim3(5, 48 / 16, 128), 64, 0, stream>>>(f2, 48, F[1], f1);
    // forward refinement
    for (int i = 0; i < 3; ++i) {
      int Cin = C[i], Ct = C[i + 1];
      convT_add<<<dim3(5, Cin / 16, 128), 64, 0, stream>>>(feats[i + 1], Cin, F[i], t2);
      conv_k3<<<dim3(5, 2, 128), 64, 0, stream>>>(t2, Cin, F[i], t3);
      conv_k3<<<dim3(5, 2, 128), 64, 0, stream>>>(feats[i], Cin, F[i], t4);
      size_t tot = (size_t)128 * Ct * LSEQ;
      f7_kernel<<<(int)((tot + 255) / 256), 256, 0, stream>>>(feats[i + 1], Cin, t2, t3, t4,
                                                              feats[i], cs[i], bv[i], pre);
      bn_stats<<<Ct, 256, 0, stream>>>(pre, Ct, stats);
      bn_apply<<<(int)((tot + 255) / 256), 256, 0, stream>>>(pre, stats, g1[i], be1[i], feats[i + 1], Ct, 1);
    }
  }

  // ---- eSE ----
  ese_mean<<<dim3(112, 128), 64, 0, stream>>>(f3, sm);
  ese_act<<<128, 128, 0, stream>>>(sm, ese_w, ese_b, am);

  // ---- fc1 (split-K, atomic) + fc2 + log_softmax ----
  hipMemsetAsync(y1, 0, 128 * 128 * sizeof(float), stream);
  fc1_gemm<<<128, 256, 0, stream>>>(f3, am, fc1_w, y1);
  fc2_lsm<<<128, 128, 0, stream>>>(y1, fc1_b, fc2_w, fc2_b, (float*)d_out);
}